// Round 14
// baseline (92.837 us; speedup 1.0000x reference)
//
#include <hip/hip_runtime.h>
#include <hip/hip_bf16.h>

#define NN 3072
#define RR 8

typedef float f4 __attribute__((ext_vector_type(4)));

// R11 structure (best, 58.3us), ONE change: fill role clones the rocclr
// fillBufferAligned geometry (7.0 TB/s measured on this buffer): each
// thread owns 64B = 4 consecutive f4 (2 pairs), 4 stores at +16B offsets.
//   blocks (bx<6, i): default-fill all (i,j) with batch[j] != batch[i]
//   block  (bx==6, i): entire same-batch range [lo,hi) of row i
__global__ __launch_bounds__(256) void frd_onepass(
    const float* __restrict__ z,       // [N, R]
    const int*   __restrict__ seg,     // [N, N]
    const int*   __restrict__ cls,     // [N]
    const int*   __restrict__ batch,   // [N]
    float*       __restrict__ out)     // [N, N, R]
{
    const int i  = blockIdx.y;
    const int bi = batch[i];                           // uniform -> scalar
    const long long rowout = (long long)i * (NN * RR);

    if (blockIdx.x < 6) {
        // ---- FILL role: 6 blocks x 256 threads x 2 pairs = 3072 pairs ----
        const int t  = blockIdx.x * 256 + threadIdx.x; // 0..1535
        const int j0 = 2 * t;                          // first pair owned

        const int bj0 = batch[j0];                     // L1/L2-hot 12 KB
        const int bj1 = batch[j0 + 1];

        const f4 v0 = {1.0f, 0.0f, 0.0f, 0.0f};
        const f4 v1 = {0.0f, 0.0f, 0.0f, 0.0f};

        f4* p = (f4*)(out + rowout) + 4 * t;           // 64B per thread
        if (bj0 != bi) { p[0] = v0; p[1] = v1; }
        if (bj1 != bi) { p[2] = v0; p[3] = v1; }
        return;
    }

    // ---- SCATTER role: full coverage of [lo,hi) (verbatim R11) ----
    int l = 0, r = NN;
    while (l < r) { const int m = (l + r) >> 1; if (batch[m] <  bi) l = m + 1; else r = m; }
    const int lo = l;
    r = NN;
    while (l < r) { const int m = (l + r) >> 1; if (batch[m] <= bi) l = m + 1; else r = m; }
    const int hi = l;

    const int h = threadIdx.x & 1;                     // which half of a pair

    // labels in [0,27): "not in {24,25,26}" <=> (< 24)
    const bool rowok = (cls[i] < 24);
    f4 a = {0.0f, 0.0f, 0.0f, 0.0f};
    if (rowok) a = *(const f4*)(z + i * RR + h * 4);

    f4 dflt;
    dflt.x = h ? 0.0f : 1.0f;
    dflt.y = 0.0f; dflt.z = 0.0f; dflt.w = 0.0f;

    // 2 threads per pair, 128 pairs per iteration, contiguous stores
    for (int p = lo + (threadIdx.x >> 1); p < hi; p += 128) {
        f4 res = dflt;
        if (rowok) {
            // seg_matrix in {0,1}; +eye -> diag never selected: (s==0 && i!=p)
            const int s = seg[(long long)i * NN + p];
            const bool pm = (s == 0) & (i != p) & (cls[p] < 24);
            if (pm) {
                const f4 b = *(const f4*)(z + p * RR + h * 4);
                res = a * b;
            }
        }
        *(f4*)(out + rowout + (long long)p * 8 + h * 4) = res;
    }
}

extern "C" void kernel_launch(void* const* d_in, const int* in_sizes, int n_in,
                              void* d_out, int out_size, void* d_ws, size_t ws_size,
                              hipStream_t stream) {
    const float* z     = (const float*)d_in[0];
    const int*   seg   = (const int*)d_in[1];
    const int*   cls   = (const int*)d_in[2];
    const int*   batch = (const int*)d_in[3];
    float* out = (float*)d_out;

    dim3 grid(7, NN);   // 6 fill blocks + 1 scatter block per row
    frd_onepass<<<grid, dim3(256), 0, stream>>>(z, seg, cls, batch, out);
}

// Round 15
// 61.657 us; speedup vs baseline: 1.5057x; 1.5057x over previous
//
#include <hip/hip_runtime.h>
#include <hip/hip_bf16.h>

#define NN 3072
#define RR 8

typedef float f4 __attribute__((ext_vector_type(4)));

#define FILL_BLOCKS 18432
#define FILL_THREADS (FILL_BLOCKS * 256)          // 4,718,592
#define FILL_TRIPS 4                              // 4 * FILL_THREADS = NN*NN*2 f4

// Kernel 1: exact rocclr fillBufferAligned geometry scaled to 302 MB.
// Grid-stride loop, 4 trips, per-instruction lane-contiguous 16B stores,
// no predication, no loads. Parity of (tid + k*FILL_THREADS) is
// thread-invariant (stride even) -> value hoisted.
__global__ __launch_bounds__(256) void fill_default(f4* __restrict__ out)
{
    const int tid = blockIdx.x * 256 + threadIdx.x;
    f4 v;
    v.x = (tid & 1) ? 0.0f : 1.0f;
    v.y = 0.0f; v.z = 0.0f; v.w = 0.0f;
#pragma unroll
    for (int k = 0; k < FILL_TRIPS; ++k) {
        out[(long long)tid + (long long)k * FILL_THREADS] = v;
    }
}

// Kernel 2 (verbatim R6 scatter, measured ~7us): batch sorted -> same-batch
// pairs are contiguous diagonal blocks (~6%). One wave per row: binary-search
// [lo,hi), scan those columns, scatter z[i]*z[j] where selected.
__global__ __launch_bounds__(256) void scatter_pairs(
    const float* __restrict__ z,       // [N, R]
    const int*   __restrict__ seg,     // [N, N]
    const int*   __restrict__ cls,     // [N]
    const int*   __restrict__ batch,   // [N]
    float*       __restrict__ out)     // [N, N, R]
{
    const int i    = (blockIdx.x * 256 + threadIdx.x) >> 6;  // one wave per row
    const int lane = threadIdx.x & 63;

    // labels in [0,27): "not in {24,25,26}" <=> (< 24)
    const int ci = cls[i];
    if (ci >= 24) return;                  // whole row stays default
    const int bi = batch[i];

    // [lo,hi) = columns with batch[j] == bi (uniform binary search, L2-hot)
    int l = 0, r = NN;
    while (l < r) { const int m = (l + r) >> 1; if (batch[m] <  bi) l = m + 1; else r = m; }
    const int lo = l;
    r = NN;
    while (l < r) { const int m = (l + r) >> 1; if (batch[m] <= bi) l = m + 1; else r = m; }
    const int hi = l;

    const f4* zip = (const f4*)(z + (long long)i * RR);
    const f4 a0 = zip[0], a1 = zip[1];
    const long long rowbase = (long long)i * NN;

    for (int j = lo + lane; j < hi; j += 64) {
        // seg_matrix in {0,1}; +eye -> diagonal never selected: (s==0 && i!=j)
        const int s = seg[rowbase + j];
        const bool pm = (s == 0) & (i != j) & (cls[j] < 24);
        if (pm) {
            const f4* zjp = (const f4*)(z + (long long)j * RR);
            f4* o = (f4*)(out + (rowbase + j) * RR);
            o[0] = a0 * zjp[0];
            o[1] = a1 * zjp[1];
        }
    }
}

extern "C" void kernel_launch(void* const* d_in, const int* in_sizes, int n_in,
                              void* d_out, int out_size, void* d_ws, size_t ws_size,
                              hipStream_t stream) {
    const float* z     = (const float*)d_in[0];
    const int*   seg   = (const int*)d_in[1];
    const int*   cls   = (const int*)d_in[2];
    const int*   batch = (const int*)d_in[3];
    float* out = (float*)d_out;

    fill_default<<<FILL_BLOCKS, 256, 0, stream>>>((f4*)out);

    // one wave per row -> 3072 waves -> 768 blocks
    scatter_pairs<<<(NN * 64) / 256, 256, 0, stream>>>(z, seg, cls, batch, out);
}

// Round 16
// 57.816 us; speedup vs baseline: 1.6057x; 1.0664x over previous
//
#include <hip/hip_runtime.h>
#include <hip/hip_bf16.h>

#define NN 3072
#define RR 8

typedef float f4 __attribute__((ext_vector_type(4)));

// Single pass, disjoint roles (R11 = 58.3us best), scatter role moved to
// bx==0 so each row's long-pole block dispatches first.
//   block  (bx==0, i): entire same-batch range [lo,hi) of row i
//                      (product where selected, default otherwise; full
//                       64B line coverage -> no partial-line RMW)
//   blocks (bx>=1, i): default to all (i,j) with batch[j] != batch[i]
//                      (pure predicated store stream, zero seg loads)
// batch is sorted, so {batch[j]==batch[i]} is exactly [lo,hi).
__global__ __launch_bounds__(256) void frd_onepass(
    const float* __restrict__ z,       // [N, R]
    const int*   __restrict__ seg,     // [N, N]
    const int*   __restrict__ cls,     // [N]
    const int*   __restrict__ batch,   // [N]
    float*       __restrict__ out)     // [N, N, R]
{
    const int i  = blockIdx.y;
    const int bi = batch[i];                           // uniform -> scalar
    const long long rowout = (long long)i * (NN * RR);
    const int h = threadIdx.x & 1;                     // which half of a pair

    if (blockIdx.x != 0) {
        // ---- FILL role: 24 blocks x 256 threads = 2 threads/pair ----
        const int t = (blockIdx.x - 1) * 256 + threadIdx.x;  // 0..6143
        const int j = t >> 1;
        const int bj = batch[j];                       // L1/L2-hot 12 KB
        if (bj != bi) {
            f4 v;
            v.x = h ? 0.0f : 1.0f;
            v.y = 0.0f; v.z = 0.0f; v.w = 0.0f;
            *(f4*)(out + rowout + (long long)t * 4) = v;   // contiguous 16B/lane
        }
        return;
    }

    // ---- SCATTER role: full coverage of [lo,hi) ----
    // uniform binary search for the row's batch block (L2-hot)
    int l = 0, r = NN;
    while (l < r) { const int m = (l + r) >> 1; if (batch[m] <  bi) l = m + 1; else r = m; }
    const int lo = l;
    r = NN;
    while (l < r) { const int m = (l + r) >> 1; if (batch[m] <= bi) l = m + 1; else r = m; }
    const int hi = l;

    // labels in [0,27): "not in {24,25,26}" <=> (< 24)
    const bool rowok = (cls[i] < 24);
    f4 a = {0.0f, 0.0f, 0.0f, 0.0f};
    if (rowok) a = *(const f4*)(z + i * RR + h * 4);

    f4 dflt;
    dflt.x = h ? 0.0f : 1.0f;
    dflt.y = 0.0f; dflt.z = 0.0f; dflt.w = 0.0f;

    // 2 threads per pair, 128 pairs per iteration, contiguous stores
    for (int p = lo + (threadIdx.x >> 1); p < hi; p += 128) {
        f4 res = dflt;
        if (rowok) {
            // seg_matrix in {0,1}; +eye -> diag never selected: (s==0 && i!=p)
            const int s = seg[(long long)i * NN + p];
            const bool pm = (s == 0) & (i != p) & (cls[p] < 24);
            if (pm) {
                const f4 b = *(const f4*)(z + p * RR + h * 4);
                res = a * b;
            }
        }
        *(f4*)(out + rowout + (long long)p * 8 + h * 4) = res;
    }
}

extern "C" void kernel_launch(void* const* d_in, const int* in_sizes, int n_in,
                              void* d_out, int out_size, void* d_ws, size_t ws_size,
                              hipStream_t stream) {
    const float* z     = (const float*)d_in[0];
    const int*   seg   = (const int*)d_in[1];
    const int*   cls   = (const int*)d_in[2];
    const int*   batch = (const int*)d_in[3];
    float* out = (float*)d_out;

    dim3 grid(25, NN);   // 1 scatter block + 24 fill blocks per row
    frd_onepass<<<grid, dim3(256), 0, stream>>>(z, seg, cls, batch, out);
}